// Round 1
// baseline (212.445 us; speedup 1.0000x reference)
//
#include <hip/hip_runtime.h>
#include <hip/hip_bf16.h>
#include <stdint.h>

#define TOK   256
#define NOBJ  64
#define NDEMO 16
#define BATCH 256
#define SEQ   1105   /* 1 + 16*65 + 64 */

typedef __bf16 bf16x8 __attribute__((ext_vector_type(8)));
typedef float  f32x4  __attribute__((ext_vector_type(4)));

// f32 -> bf16 round-to-nearest-even, two at a time, packed into u32
static __device__ __forceinline__ unsigned pack_bf16x2(float a, float b) {
    unsigned ua = __float_as_uint(a);
    unsigned ub = __float_as_uint(b);
    unsigned ra = (ua + 0x7FFFu + ((ua >> 16) & 1u)) >> 16;
    unsigned rb = (ub + 0x7FFFu + ((ub >> 16) & 1u)) >> 16;
    return (ra & 0xFFFFu) | (rb << 16);
}

static __device__ __forceinline__ uint16_t f32_to_bf16_bits(float a) {
    unsigned ua = __float_as_uint(a);
    return (uint16_t)((ua + 0x7FFFu + ((ua >> 16) & 1u)) >> 16);
}

// ---------------------------------------------------------------------------
// Prologue: W_obj (f32, [k=256][t=256]) -> Wt (bf16 bits, [t=256][k=256])
// ---------------------------------------------------------------------------
__global__ void wconv_kernel(const float* __restrict__ W, uint16_t* __restrict__ Wt) {
    int n = blockIdx.x;    // output token index t
    int k = threadIdx.x;   // feature index
    Wt[n * TOK + k] = f32_to_bf16_bits(W[k * TOK + n]);
}

// ---------------------------------------------------------------------------
// Main kernel: one block = one 64-row x 256-col output tile through W_obj.
// blocks 0..4095   : demo-object groups (d = blk>>8, b = blk&255)
// blocks 4096..4351: current-object groups (b = blk-4096)
// ---------------------------------------------------------------------------
__global__ __launch_bounds__(256, 2) void obj_gemm_kernel(
    const float* __restrict__ demo_obj,   // (16,256,64,256)
    const float* __restrict__ cur,        // (256,64,256)
    const float* __restrict__ bias,       // (256,)
    const __bf16* __restrict__ Wt,        // (256 tok, 256 k) bf16
    float* __restrict__ out)              // (256,1105,256)
{
    int gid = blockIdx.x;
    const float* srcA;
    int row_base;
    if (gid < NDEMO * BATCH) {
        int d = gid >> 8, b = gid & 255;
        srcA = demo_obj + (size_t)(d * BATCH + b) * (NOBJ * TOK);
        row_base = b * SEQ + 1 + d * (NOBJ + 1);
    } else {
        int b = gid - NDEMO * BATCH;
        srcA = cur + (size_t)b * (NOBJ * TOK);
        row_base = b * SEQ + 1 + NDEMO * (NOBJ + 1);
    }

    // 64 rows x 256 bf16 (512 B/row), XOR-swizzled 16B chunks: byte ^= (row&7)<<4
    __shared__ __align__(16) unsigned char lds[64 * 512];

    int t = threadIdx.x;

    // ---- stage A: f32 -> bf16 into LDS (coalesced 32B/lane global reads) ----
#pragma unroll
    for (int i = 0; i < 8; ++i) {
        int chunk = i * 256 + t;          // 2048 chunks of 8 f32
        int row = chunk >> 5;             // 32 chunks per row
        int kc  = chunk & 31;
        const float4* p = reinterpret_cast<const float4*>(srcA + (size_t)chunk * 8);
        float4 v0 = p[0];
        float4 v1 = p[1];
        uint4 w;
        w.x = pack_bf16x2(v0.x, v0.y);
        w.y = pack_bf16x2(v0.z, v0.w);
        w.z = pack_bf16x2(v1.x, v1.y);
        w.w = pack_bf16x2(v1.z, v1.w);
        unsigned off = (unsigned)(row * 512 + kc * 16) ^ (unsigned)((row & 7) << 4);
        *reinterpret_cast<uint4*>(lds + off) = w;
    }
    __syncthreads();

    int wave = t >> 6;
    int lane = t & 63;
    int l15 = lane & 15;
    int l4  = lane >> 4;
    int n0  = wave * 64;   // this wave's 64 output columns

    // ---- preload B fragments from global (L2-hot, 128 VGPR) ----
    bf16x8 bf[4][8];   // [n-rep][k-step]
#pragma unroll
    for (int j = 0; j < 4; ++j) {
        const __bf16* wrow = Wt + (size_t)(n0 + j * 16 + l15) * TOK;
#pragma unroll
        for (int s = 0; s < 8; ++s) {
            bf[j][s] = *reinterpret_cast<const bf16x8*>(wrow + s * 32 + l4 * 8);
        }
    }

    f32x4 acc[4][4];
#pragma unroll
    for (int i = 0; i < 4; ++i)
#pragma unroll
        for (int j = 0; j < 4; ++j) {
            f32x4 z = {0.0f, 0.0f, 0.0f, 0.0f};
            acc[i][j] = z;
        }

    // ---- K loop: 8 steps of K=32 ----
#pragma unroll
    for (int s = 0; s < 8; ++s) {
        bf16x8 a[4];
#pragma unroll
        for (int i = 0; i < 4; ++i) {
            int row = i * 16 + l15;
            unsigned off = (unsigned)(row * 512 + (s * 4 + l4) * 16) ^ (unsigned)((row & 7) << 4);
            a[i] = *reinterpret_cast<const bf16x8*>(lds + off);
        }
#pragma unroll
        for (int i = 0; i < 4; ++i)
#pragma unroll
            for (int j = 0; j < 4; ++j)
                acc[i][j] = __builtin_amdgcn_mfma_f32_16x16x32_bf16(a[i], bf[j][s], acc[i][j], 0, 0, 0);
    }

    // ---- epilogue: bias + store f32 ----
    float bv[4];
#pragma unroll
    for (int j = 0; j < 4; ++j) bv[j] = bias[n0 + j * 16 + l15];

#pragma unroll
    for (int i = 0; i < 4; ++i) {
#pragma unroll
        for (int j = 0; j < 4; ++j) {
            int col = n0 + j * 16 + l15;
#pragma unroll
            for (int r = 0; r < 4; ++r) {
                int row = row_base + i * 16 + l4 * 4 + r;
                out[(size_t)row * TOK + col] = acc[i][j][r] + bv[j];
            }
        }
    }
}

// ---------------------------------------------------------------------------
// Action rows: out[b, (d+1)*65, t] = sum_{k<7} act[d,b,k]*W_act[k,t] + b_act[t]
// ---------------------------------------------------------------------------
__global__ void act_kernel(const float* __restrict__ act,
                           const float* __restrict__ W,
                           const float* __restrict__ bias,
                           float* __restrict__ out) {
    int g = blockIdx.x;           // d*256 + b
    int d = g >> 8, b = g & 255;
    int t = threadIdx.x;
    const float* a = act + (size_t)g * 7;
    float v = bias[t];
#pragma unroll
    for (int k = 0; k < 7; ++k) v += a[k] * W[k * TOK + t];
    out[(size_t)(b * SEQ + (d + 1) * (NOBJ + 1)) * TOK + t] = v;
}

// ---------------------------------------------------------------------------
// Instr row: out[b, 0, t] = sum_{k<768} instr[b,k]*W_instr[k,t] + b_instr[t]
// ---------------------------------------------------------------------------
__global__ void instr_kernel(const float* __restrict__ instr,
                             const float* __restrict__ W,
                             const float* __restrict__ bias,
                             float* __restrict__ out) {
    int b = blockIdx.x;
    int t = threadIdx.x;
    __shared__ float row[768];
    for (int i = t; i < 768; i += 256) row[i] = instr[(size_t)b * 768 + i];
    __syncthreads();
    float v = bias[t];
#pragma unroll 8
    for (int k = 0; k < 768; ++k) v += row[k] * W[k * TOK + t];
    out[(size_t)b * SEQ * TOK + t] = v;
}

extern "C" void kernel_launch(void* const* d_in, const int* in_sizes, int n_in,
                              void* d_out, int out_size, void* d_ws, size_t ws_size,
                              hipStream_t stream) {
    (void)in_sizes; (void)n_in; (void)out_size; (void)ws_size;
    const float* instr    = (const float*)d_in[0];
    const float* demo_obj = (const float*)d_in[1];
    const float* demo_act = (const float*)d_in[2];
    const float* cur      = (const float*)d_in[3];
    const float* W_instr  = (const float*)d_in[4];
    const float* b_instr  = (const float*)d_in[5];
    const float* W_act    = (const float*)d_in[6];
    const float* b_act    = (const float*)d_in[7];
    const float* W_obj    = (const float*)d_in[8];
    const float* b_obj    = (const float*)d_in[9];
    float* out = (float*)d_out;

    uint16_t* Wt = (uint16_t*)d_ws;   // 256*256 bf16 = 128 KB

    wconv_kernel<<<256, 256, 0, stream>>>(W_obj, Wt);
    obj_gemm_kernel<<<NDEMO * BATCH + BATCH, 256, 0, stream>>>(
        demo_obj, cur, b_obj, (const __bf16*)d_ws, out);
    act_kernel<<<NDEMO * BATCH, 256, 0, stream>>>(demo_act, W_act, b_act, out);
    instr_kernel<<<BATCH, 256, 0, stream>>>(instr, W_instr, b_instr, out);
}